// Round 1
// baseline (1095.844 us; speedup 1.0000x reference)
//
#include <hip/hip_runtime.h>
#include <hip/hip_bf16.h>
#include <cstdint>

#define NL 2
#define DM 768
#define DI 1536
#define DS 16
#define DD 48
#define DCONV 4
#define BB 2
#define LL 1024
#define MROWS (BB*LL)    // 2048
#define DBCW (DD + 2*DS) // 80

typedef __bf16 bf16x8 __attribute__((ext_vector_type(8)));
typedef float f32x4 __attribute__((ext_vector_type(4)));
using bf16 = __hip_bfloat16;

__device__ __forceinline__ float softplusf(float x) {
  return (x > 20.f) ? x : log1pf(__expf(x));
}

// ---------------------------------------------------------------------------
// fp32 -> bf16 elementwise convert
// ---------------------------------------------------------------------------
__global__ __launch_bounds__(256)
void f2b_kernel(const float* __restrict__ in, bf16* __restrict__ out, int n)
{
  int i = blockIdx.x * 256 + threadIdx.x;
  if (i < n) out[i] = __float2bfloat16(in[i]);
}

// ---------------------------------------------------------------------------
// RMSNorm: one block per row of 768, output bf16
// ---------------------------------------------------------------------------
__global__ __launch_bounds__(256)
void rmsnorm_kernel(const float* __restrict__ x, const float* __restrict__ w,
                    bf16* __restrict__ out)
{
  const int row = blockIdx.x;
  const float* xr = x + (size_t)row * DM;
  const int t = threadIdx.x;
  float v0 = xr[t], v1 = xr[t + 256], v2 = xr[t + 512];
  float ss = v0*v0 + v1*v1 + v2*v2;
  #pragma unroll
  for (int off = 32; off > 0; off >>= 1) ss += __shfl_down(ss, off);
  __shared__ float sred[4];
  if ((t & 63) == 0) sred[t >> 6] = ss;
  __syncthreads();
  const float scale = rsqrtf((sred[0]+sred[1]+sred[2]+sred[3]) * (1.f/DM) + 1e-5f);
  out[(size_t)row*DM + t      ] = __float2bfloat16(v0 * scale * w[t]);
  out[(size_t)row*DM + t + 256] = __float2bfloat16(v1 * scale * w[t + 256]);
  out[(size_t)row*DM + t + 512] = __float2bfloat16(v2 * scale * w[t + 512]);
}

// ---------------------------------------------------------------------------
// Causal depthwise conv (K=4) + SiLU, reads xi = xz[:, 0:DI]
// Writes fp32 (for scan) and bf16 (for x_proj GEMM)
// ---------------------------------------------------------------------------
__global__ __launch_bounds__(256)
void conv_silu_kernel(const float* __restrict__ xz, const float* __restrict__ cw,
                      const float* __restrict__ cb,
                      float* __restrict__ xof, bf16* __restrict__ xob)
{
  const int idx = blockIdx.x * 256 + threadIdx.x;   // over MROWS*DI
  const int d = idx % DI;
  const int row = idx / DI;   // b*LL + l
  const int l = row % LL;
  float acc = cb[d];
  #pragma unroll
  for (int k = 0; k < DCONV; ++k) {
    int ll = l - (DCONV-1) + k;
    if (ll >= 0)
      acc += cw[d*DCONV + k] * xz[(size_t)(row - (DCONV-1) + k) * (2*DI) + d];
  }
  const float s = acc / (1.f + __expf(-acc));
  xof[idx] = s;
  xob[idx] = __float2bfloat16(s);
}

// ---------------------------------------------------------------------------
// bf16 MFMA GEMM: C[M,N] = A[M,K] * W[N,K]^T  (both row-major, B^T form)
// 64x64x32 tile, 4 waves, each wave a 32x32 quadrant (2x2 MFMA 16x16x32).
// MODE 0: plain fp32 store
// MODE 2: C = softplus(acc + bias[col])      (dt projection)
// MODE 3: C = acc + res[idx]                 (out projection + residual)
// M is always a multiple of 64 here; N,K guarded.
// ---------------------------------------------------------------------------
template<int MODE>
__global__ __launch_bounds__(256)
void gemm_bt(const bf16* __restrict__ A, int lda,
             const bf16* __restrict__ W, int ldw,
             float* __restrict__ C, int ldc,
             int N, int K,
             const float* __restrict__ bias,
             const float* __restrict__ res)
{
  __shared__ __align__(16) bf16 As[64][40];
  __shared__ __align__(16) bf16 Ws[64][40];
  const int tid = threadIdx.x;
  const int m0 = blockIdx.x * 64;
  const int n0 = blockIdx.y * 64;
  const int wave = tid >> 6;
  const int lane = tid & 63;
  const int wr = (wave >> 1) * 32;
  const int wc = (wave & 1) * 32;
  const int l16 = lane & 15;
  const int quad = lane >> 4;
  const int srow = tid >> 2;         // 0..63
  const int scol = (tid & 3) * 8;    // 0,8,16,24

  f32x4 acc[2][2] = {};

  for (int k0 = 0; k0 < K; k0 += 32) {
    // stage A tile (rows always valid; K guarded)
    {
      const bf16* src = A + (size_t)(m0 + srow) * lda + (k0 + scol);
      bf16* dst = &As[srow][scol];
      if (k0 + scol + 8 <= K) {
        *reinterpret_cast<uint4*>(dst) = *reinterpret_cast<const uint4*>(src);
      } else {
        #pragma unroll
        for (int j = 0; j < 8; ++j)
          dst[j] = (k0 + scol + j < K) ? src[j] : __float2bfloat16(0.f);
      }
    }
    // stage W tile (N and K guarded)
    {
      const int n = n0 + srow;
      bf16* dst = &Ws[srow][scol];
      if (n < N && (k0 + scol + 8 <= K)) {
        *reinterpret_cast<uint4*>(dst) =
            *reinterpret_cast<const uint4*>(W + (size_t)n * ldw + (k0 + scol));
      } else {
        #pragma unroll
        for (int j = 0; j < 8; ++j)
          dst[j] = (n < N && (k0 + scol + j) < K)
                   ? W[(size_t)n * ldw + k0 + scol + j] : __float2bfloat16(0.f);
      }
    }
    __syncthreads();

    bf16x8 af[2], wf[2];
    #pragma unroll
    for (int i = 0; i < 2; ++i)
      af[i] = *reinterpret_cast<const bf16x8*>(&As[wr + i*16 + l16][quad*8]);
    #pragma unroll
    for (int j = 0; j < 2; ++j)
      wf[j] = *reinterpret_cast<const bf16x8*>(&Ws[wc + j*16 + l16][quad*8]);
    #pragma unroll
    for (int i = 0; i < 2; ++i)
      #pragma unroll
      for (int j = 0; j < 2; ++j)
        acc[i][j] = __builtin_amdgcn_mfma_f32_16x16x32_bf16(af[i], wf[j], acc[i][j], 0, 0, 0);
    __syncthreads();
  }

  #pragma unroll
  for (int i = 0; i < 2; ++i) {
    #pragma unroll
    for (int j = 0; j < 2; ++j) {
      const int col = n0 + wc + j*16 + l16;
      if (col >= N) continue;
      #pragma unroll
      for (int r = 0; r < 4; ++r) {
        const int row = m0 + wr + i*16 + quad*4 + r;
        float v = acc[i][j][r];
        const size_t idx = (size_t)row * ldc + col;
        if (MODE == 2) v = softplusf(v + bias[col]);
        else if (MODE == 3) v += res[idx];
        C[idx] = v;
      }
    }
  }
}

// ---------------------------------------------------------------------------
// SSM scan: lane per (b,d,n); 16-lane groups; y reduced via shfl_xor.
// Epilogue fused: out = (y + D*x) * silu(z), written directly as bf16.
// ---------------------------------------------------------------------------
__global__ __launch_bounds__(256)
void scan_kernel(const float* __restrict__ delta, const float* __restrict__ xi,
                 const float* __restrict__ dbc, const float* __restrict__ A_log,
                 const float* __restrict__ Dp, const float* __restrict__ xz,
                 bf16* __restrict__ outb)
{
  const int tid = threadIdx.x;
  const int n = tid & 15;
  const int gid = blockIdx.x * 16 + (tid >> 4);
  const int b = gid / DI;
  const int d = gid % DI;
  const float An = -__expf(A_log[d*DS + n]) * 1.44269504f;  // pre-scaled for exp2
  const float Dd = Dp[d];
  const float* dptr = delta + (size_t)b*LL*DI + d;
  const float* xptr = xi    + (size_t)b*LL*DI + d;
  const float* bptr = dbc   + (size_t)b*LL*DBCW + DD + n;
  const float* cptr = dbc   + (size_t)b*LL*DBCW + DD + DS + n;
  const float* zptr = xz    + (size_t)b*LL*(2*DI) + DI + d;
  bf16* optr = outb + (size_t)b*LL*DI + d;

  float h = 0.f;
  float dl = dptr[0], xv = xptr[0], Bv = bptr[0], Cv = cptr[0], zv = zptr[0];
  for (int t = 0; t < LL; ++t) {
    float dl_n = 0.f, xv_n = 0.f, Bv_n = 0.f, Cv_n = 0.f, zv_n = 0.f;
    if (t + 1 < LL) {
      dl_n = dptr[(size_t)(t+1)*DI];
      xv_n = xptr[(size_t)(t+1)*DI];
      Bv_n = bptr[(size_t)(t+1)*DBCW];
      Cv_n = cptr[(size_t)(t+1)*DBCW];
      zv_n = zptr[(size_t)(t+1)*(2*DI)];
    }
    h = exp2f(dl * An) * h + dl * Bv * xv;
    float y = h * Cv;
    y += __shfl_xor(y, 1);
    y += __shfl_xor(y, 2);
    y += __shfl_xor(y, 4);
    y += __shfl_xor(y, 8);
    if (n == 0) {
      const float o = (y + Dd * xv) * (zv / (1.f + __expf(-zv)));
      optr[(size_t)t*DI] = __float2bfloat16(o);
    }
    dl = dl_n; xv = xv_n; Bv = Bv_n; Cv = Cv_n; zv = zv_n;
  }
}

// ---------------------------------------------------------------------------
extern "C" void kernel_launch(void* const* d_in, const int* in_sizes, int n_in,
                              void* d_out, int out_size, void* d_ws, size_t ws_size,
                              hipStream_t stream)
{
  const float* x_in   = (const float*)d_in[0];
  const float* w_inp  = (const float*)d_in[1];
  const float* w_conv = (const float*)d_in[2];
  const float* b_conv = (const float*)d_in[3];
  const float* w_xprj = (const float*)d_in[4];
  const float* w_dtp  = (const float*)d_in[5];
  const float* b_dt   = (const float*)d_in[6];
  const float* a_log  = (const float*)d_in[7];
  const float* d_par  = (const float*)d_in[8];
  const float* w_outp = (const float*)d_in[9];
  const float* w_norm = (const float*)d_in[10];
  float* xfinal = (float*)d_out;

  char* ws = (char*)d_ws;
  size_t off = 0;
  auto alloc = [&](size_t bytes) -> void* {
    void* p = ws + off;
    off += (bytes + 255) & ~(size_t)255;
    return p;
  };
  bf16*  wb_in  = (bf16*) alloc((size_t)NL*2*DI*DM*2);
  bf16*  wb_xp  = (bf16*) alloc((size_t)NL*DBCW*DI*2);
  bf16*  wb_dt  = (bf16*) alloc((size_t)NL*DI*DD*2);
  bf16*  wb_out = (bf16*) alloc((size_t)NL*DM*DI*2);
  bf16*  xn     = (bf16*) alloc((size_t)MROWS*DM*2);
  float* xzb    = (float*)alloc((size_t)MROWS*2*DI*4);
  float* xcf    = (float*)alloc((size_t)MROWS*DI*4);
  bf16*  xcb    = (bf16*) alloc((size_t)MROWS*DI*2);
  float* dbcf   = (float*)alloc((size_t)MROWS*DBCW*4);
  bf16*  dbcb   = (bf16*) alloc((size_t)MROWS*DBCW*2);
  float* dlt    = (float*)alloc((size_t)MROWS*DI*4);
  bf16*  scb    = (bf16*) alloc((size_t)MROWS*DI*2);
  float* x1     = (float*)alloc((size_t)MROWS*DM*4);

  // weights -> bf16 (once per launch; inputs restored before every call)
  f2b_kernel<<<(NL*2*DI*DM + 255)/256, 256, 0, stream>>>(w_inp,  wb_in,  NL*2*DI*DM);
  f2b_kernel<<<(NL*DBCW*DI + 255)/256, 256, 0, stream>>>(w_xprj, wb_xp,  NL*DBCW*DI);
  f2b_kernel<<<(NL*DI*DD   + 255)/256, 256, 0, stream>>>(w_dtp,  wb_dt,  NL*DI*DD);
  f2b_kernel<<<(NL*DM*DI   + 255)/256, 256, 0, stream>>>(w_outp, wb_out, NL*DM*DI);

  const float* xprev = x_in;
  for (int l = 0; l < NL; ++l) {
    rmsnorm_kernel<<<MROWS, 256, 0, stream>>>(xprev, w_norm + l*DM, xn);

    // xz = xn @ in_proj^T : [2048, 3072]
    gemm_bt<0><<<dim3(MROWS/64, (2*DI)/64), 256, 0, stream>>>(
        xn, DM, wb_in + (size_t)l*2*DI*DM, DM, xzb, 2*DI, 2*DI, DM, nullptr, nullptr);

    conv_silu_kernel<<<(MROWS*DI)/256, 256, 0, stream>>>(
        xzb, w_conv + l*DI*DCONV, b_conv + l*DI, xcf, xcb);

    // dbc = xi_conv @ xproj^T : [2048, 80]
    gemm_bt<0><<<dim3(MROWS/64, 2), 256, 0, stream>>>(
        xcb, DI, wb_xp + (size_t)l*DBCW*DI, DI, dbcf, DBCW, DBCW, DI, nullptr, nullptr);

    f2b_kernel<<<(MROWS*DBCW + 255)/256, 256, 0, stream>>>(dbcf, dbcb, MROWS*DBCW);

    // delta = softplus(dbc[:, :48] @ dt_w^T + dt_b) : [2048, 1536]
    gemm_bt<2><<<dim3(MROWS/64, DI/64), 256, 0, stream>>>(
        dbcb, DBCW, wb_dt + (size_t)l*DI*DD, DD, dlt, DI, DI, DD, b_dt + l*DI, nullptr);

    scan_kernel<<<(BB*DI)/16, 256, 0, stream>>>(
        dlt, xcf, dbcf, a_log + (size_t)l*DI*DS, d_par + l*DI, xzb, scb);

    // x_next = x_prev + (scan_out) @ out_proj^T : [2048, 768]
    float* xout = (l == NL-1) ? xfinal : x1;
    gemm_bt<3><<<dim3(MROWS/64, DM/64), 256, 0, stream>>>(
        scb, DI, wb_out + (size_t)l*DM*DI, DI, xout, DM, DM, DI, nullptr, xprev);

    xprev = x1;
  }
}

// Round 2
// 569.793 us; speedup vs baseline: 1.9232x; 1.9232x over previous
//
#include <hip/hip_runtime.h>
#include <hip/hip_bf16.h>
#include <cstdint>

#define NL 2
#define DM 768
#define DI 1536
#define DS 16
#define DD 48
#define DCONV 4
#define BB 2
#define LL 1024
#define MROWS (BB*LL)    // 2048
#define DBCW (DD + 2*DS) // 80
#define TC 128           // scan chunk length
#define NC (LL/TC)       // 8 chunks

typedef __bf16 bf16x8 __attribute__((ext_vector_type(8)));
typedef float f32x4 __attribute__((ext_vector_type(4)));
using bf16 = __hip_bfloat16;

__device__ __forceinline__ float softplusf(float x) {
  return (x > 20.f) ? x : log1pf(__expf(x));
}

// ---------------------------------------------------------------------------
// fp32 -> bf16 elementwise convert
// ---------------------------------------------------------------------------
__global__ __launch_bounds__(256)
void f2b_kernel(const float* __restrict__ in, bf16* __restrict__ out, int n)
{
  int i = blockIdx.x * 256 + threadIdx.x;
  if (i < n) out[i] = __float2bfloat16(in[i]);
}

// ---------------------------------------------------------------------------
// RMSNorm: one block per row of 768, output bf16
// ---------------------------------------------------------------------------
__global__ __launch_bounds__(256)
void rmsnorm_kernel(const float* __restrict__ x, const float* __restrict__ w,
                    bf16* __restrict__ out)
{
  const int row = blockIdx.x;
  const float* xr = x + (size_t)row * DM;
  const int t = threadIdx.x;
  float v0 = xr[t], v1 = xr[t + 256], v2 = xr[t + 512];
  float ss = v0*v0 + v1*v1 + v2*v2;
  #pragma unroll
  for (int off = 32; off > 0; off >>= 1) ss += __shfl_down(ss, off);
  __shared__ float sred[4];
  if ((t & 63) == 0) sred[t >> 6] = ss;
  __syncthreads();
  const float scale = rsqrtf((sred[0]+sred[1]+sred[2]+sred[3]) * (1.f/DM) + 1e-5f);
  out[(size_t)row*DM + t      ] = __float2bfloat16(v0 * scale * w[t]);
  out[(size_t)row*DM + t + 256] = __float2bfloat16(v1 * scale * w[t + 256]);
  out[(size_t)row*DM + t + 512] = __float2bfloat16(v2 * scale * w[t + 512]);
}

// ---------------------------------------------------------------------------
// Causal depthwise conv (K=4) + SiLU, reads xi = xz[:, 0:DI]
// Writes fp32 (for scan) and bf16 (for x_proj GEMM)
// ---------------------------------------------------------------------------
__global__ __launch_bounds__(256)
void conv_silu_kernel(const float* __restrict__ xz, const float* __restrict__ cw,
                      const float* __restrict__ cb,
                      float* __restrict__ xof, bf16* __restrict__ xob)
{
  const int idx = blockIdx.x * 256 + threadIdx.x;   // over MROWS*DI
  const int d = idx % DI;
  const int row = idx / DI;   // b*LL + l
  const int l = row % LL;
  float acc = cb[d];
  #pragma unroll
  for (int k = 0; k < DCONV; ++k) {
    int ll = l - (DCONV-1) + k;
    if (ll >= 0)
      acc += cw[d*DCONV + k] * xz[(size_t)(row - (DCONV-1) + k) * (2*DI) + d];
  }
  const float s = acc / (1.f + __expf(-acc));
  xof[idx] = s;
  xob[idx] = __float2bfloat16(s);
}

// ---------------------------------------------------------------------------
// bf16 MFMA GEMM: C[M,N] = A[M,K] * W[N,K]^T  (both row-major, B^T form)
// 64x64x32 tile, 4 waves, each wave a 32x32 quadrant (2x2 MFMA 16x16x32).
// MODE 0: plain fp32 store
// MODE 2: C = softplus(acc + bias[col])      (dt projection)
// MODE 3: C = acc + res[idx]                 (out projection + residual)
// ---------------------------------------------------------------------------
template<int MODE>
__global__ __launch_bounds__(256)
void gemm_bt(const bf16* __restrict__ A, int lda,
             const bf16* __restrict__ W, int ldw,
             float* __restrict__ C, int ldc,
             int N, int K,
             const float* __restrict__ bias,
             const float* __restrict__ res)
{
  __shared__ __align__(16) bf16 As[64][40];
  __shared__ __align__(16) bf16 Ws[64][40];
  const int tid = threadIdx.x;
  const int m0 = blockIdx.x * 64;
  const int n0 = blockIdx.y * 64;
  const int wave = tid >> 6;
  const int lane = tid & 63;
  const int wr = (wave >> 1) * 32;
  const int wc = (wave & 1) * 32;
  const int l16 = lane & 15;
  const int quad = lane >> 4;
  const int srow = tid >> 2;         // 0..63
  const int scol = (tid & 3) * 8;    // 0,8,16,24

  f32x4 acc[2][2] = {};

  for (int k0 = 0; k0 < K; k0 += 32) {
    {
      const bf16* src = A + (size_t)(m0 + srow) * lda + (k0 + scol);
      bf16* dst = &As[srow][scol];
      if (k0 + scol + 8 <= K) {
        *reinterpret_cast<uint4*>(dst) = *reinterpret_cast<const uint4*>(src);
      } else {
        #pragma unroll
        for (int j = 0; j < 8; ++j)
          dst[j] = (k0 + scol + j < K) ? src[j] : __float2bfloat16(0.f);
      }
    }
    {
      const int n = n0 + srow;
      bf16* dst = &Ws[srow][scol];
      if (n < N && (k0 + scol + 8 <= K)) {
        *reinterpret_cast<uint4*>(dst) =
            *reinterpret_cast<const uint4*>(W + (size_t)n * ldw + (k0 + scol));
      } else {
        #pragma unroll
        for (int j = 0; j < 8; ++j)
          dst[j] = (n < N && (k0 + scol + j) < K)
                   ? W[(size_t)n * ldw + k0 + scol + j] : __float2bfloat16(0.f);
      }
    }
    __syncthreads();

    bf16x8 af[2], wf[2];
    #pragma unroll
    for (int i = 0; i < 2; ++i)
      af[i] = *reinterpret_cast<const bf16x8*>(&As[wr + i*16 + l16][quad*8]);
    #pragma unroll
    for (int j = 0; j < 2; ++j)
      wf[j] = *reinterpret_cast<const bf16x8*>(&Ws[wc + j*16 + l16][quad*8]);
    #pragma unroll
    for (int i = 0; i < 2; ++i)
      #pragma unroll
      for (int j = 0; j < 2; ++j)
        acc[i][j] = __builtin_amdgcn_mfma_f32_16x16x32_bf16(af[i], wf[j], acc[i][j], 0, 0, 0);
    __syncthreads();
  }

  #pragma unroll
  for (int i = 0; i < 2; ++i) {
    #pragma unroll
    for (int j = 0; j < 2; ++j) {
      const int col = n0 + wc + j*16 + l16;
      if (col >= N) continue;
      #pragma unroll
      for (int r = 0; r < 4; ++r) {
        const int row = m0 + wr + i*16 + quad*4 + r;
        float v = acc[i][j][r];
        const size_t idx = (size_t)row * ldc + col;
        if (MODE == 2) v = softplusf(v + bias[col]);
        else if (MODE == 3) v += res[idx];
        C[idx] = v;
      }
    }
  }
}

// ---------------------------------------------------------------------------
// Chunked parallel scan.
// Group of 16 lanes per (b, d, chunk); gid = (b*NC + c)*DI + d  (d fastest
// so delta/xi/z loads coalesce across the 16 groups of a block).
//
// pass1: scan chunk with h_in = 0; emit P = prod(dA), H = h_out   per n.
// fix:   lane per (b,d,n); serial over the NC chunk summaries; overwrite
//        H[c] with the chunk's true h_in.
// pass2: re-scan chunk from h_in = H[c]; compute y, reduce over n, fused
//        epilogue out = (y + D*x) * silu(z) -> bf16.
// ---------------------------------------------------------------------------
__global__ __launch_bounds__(256)
void scan_pass1(const float* __restrict__ delta, const float* __restrict__ xi,
                const float* __restrict__ dbc, const float* __restrict__ A_log,
                float* __restrict__ P, float* __restrict__ H)
{
  const int tid = threadIdx.x;
  const int n = tid & 15;
  const int gid = blockIdx.x * 16 + (tid >> 4);
  const int d = gid % DI;
  const int bc = gid / DI;
  const int c = bc % NC;
  const int b = bc / NC;
  const float An = -__expf(A_log[d*DS + n]) * 1.44269504f;
  const int t0 = c * TC;
  const float* dptr = delta + ((size_t)b*LL + t0)*DI + d;
  const float* xptr = xi    + ((size_t)b*LL + t0)*DI + d;
  const float* bptr = dbc   + ((size_t)b*LL + t0)*DBCW + DD + n;

  float h = 0.f, p = 1.f;
  float dl = dptr[0], xv = xptr[0], Bv = bptr[0];
  for (int t = 0; t < TC; ++t) {
    float dl_n = 0.f, xv_n = 0.f, Bv_n = 0.f;
    if (t + 1 < TC) {
      dl_n = dptr[(size_t)(t+1)*DI];
      xv_n = xptr[(size_t)(t+1)*DI];
      Bv_n = bptr[(size_t)(t+1)*DBCW];
    }
    const float dA = exp2f(dl * An);
    h = dA * h + dl * Bv * xv;
    p *= dA;
    dl = dl_n; xv = xv_n; Bv = Bv_n;
  }
  P[(size_t)gid*DS + n] = p;
  H[(size_t)gid*DS + n] = h;
}

__global__ __launch_bounds__(256)
void scan_fix(float* __restrict__ P, float* __restrict__ H)
{
  const int idx = blockIdx.x * 256 + threadIdx.x;   // over BB*DI*DS
  const int n = idx & 15;
  const int d = (idx >> 4) % DI;
  const int b = idx / (16 * DI);
  float hin = 0.f;
  #pragma unroll
  for (int c = 0; c < NC; ++c) {
    const size_t ic = ((size_t)(b*NC + c)*DI + d)*DS + n;
    const float Pv = P[ic];
    const float Hv = H[ic];
    H[ic] = hin;
    hin = Pv * hin + Hv;
  }
}

__global__ __launch_bounds__(256)
void scan_pass2(const float* __restrict__ delta, const float* __restrict__ xi,
                const float* __restrict__ dbc, const float* __restrict__ A_log,
                const float* __restrict__ H, const float* __restrict__ Dp,
                const float* __restrict__ xz, bf16* __restrict__ outb)
{
  const int tid = threadIdx.x;
  const int n = tid & 15;
  const int gid = blockIdx.x * 16 + (tid >> 4);
  const int d = gid % DI;
  const int bc = gid / DI;
  const int c = bc % NC;
  const int b = bc / NC;
  const float An = -__expf(A_log[d*DS + n]) * 1.44269504f;
  const float Dd = Dp[d];
  const int t0 = c * TC;
  const float* dptr = delta + ((size_t)b*LL + t0)*DI + d;
  const float* xptr = xi    + ((size_t)b*LL + t0)*DI + d;
  const float* bptr = dbc   + ((size_t)b*LL + t0)*DBCW + DD + n;
  const float* cptr = dbc   + ((size_t)b*LL + t0)*DBCW + DD + DS + n;
  const float* zptr = xz    + ((size_t)b*LL + t0)*(2*DI) + DI + d;
  bf16* optr = outb + ((size_t)b*LL + t0)*DI + d;

  float h = H[(size_t)gid*DS + n];
  float dl = dptr[0], xv = xptr[0], Bv = bptr[0], Cv = cptr[0], zv = zptr[0];
  for (int t = 0; t < TC; ++t) {
    float dl_n = 0.f, xv_n = 0.f, Bv_n = 0.f, Cv_n = 0.f, zv_n = 0.f;
    if (t + 1 < TC) {
      dl_n = dptr[(size_t)(t+1)*DI];
      xv_n = xptr[(size_t)(t+1)*DI];
      Bv_n = bptr[(size_t)(t+1)*DBCW];
      Cv_n = cptr[(size_t)(t+1)*DBCW];
      zv_n = zptr[(size_t)(t+1)*(2*DI)];
    }
    h = exp2f(dl * An) * h + dl * Bv * xv;
    float y = h * Cv;
    y += __shfl_xor(y, 1);
    y += __shfl_xor(y, 2);
    y += __shfl_xor(y, 4);
    y += __shfl_xor(y, 8);
    if (n == 0) {
      const float o = (y + Dd * xv) * (zv / (1.f + __expf(-zv)));
      optr[(size_t)t*DI] = __float2bfloat16(o);
    }
    dl = dl_n; xv = xv_n; Bv = Bv_n; Cv = Cv_n; zv = zv_n;
  }
}

// ---------------------------------------------------------------------------
extern "C" void kernel_launch(void* const* d_in, const int* in_sizes, int n_in,
                              void* d_out, int out_size, void* d_ws, size_t ws_size,
                              hipStream_t stream)
{
  const float* x_in   = (const float*)d_in[0];
  const float* w_inp  = (const float*)d_in[1];
  const float* w_conv = (const float*)d_in[2];
  const float* b_conv = (const float*)d_in[3];
  const float* w_xprj = (const float*)d_in[4];
  const float* w_dtp  = (const float*)d_in[5];
  const float* b_dt   = (const float*)d_in[6];
  const float* a_log  = (const float*)d_in[7];
  const float* d_par  = (const float*)d_in[8];
  const float* w_outp = (const float*)d_in[9];
  const float* w_norm = (const float*)d_in[10];
  float* xfinal = (float*)d_out;

  char* ws = (char*)d_ws;
  size_t off = 0;
  auto alloc = [&](size_t bytes) -> void* {
    void* p = ws + off;
    off += (bytes + 255) & ~(size_t)255;
    return p;
  };
  bf16*  wb_in  = (bf16*) alloc((size_t)NL*2*DI*DM*2);
  bf16*  wb_xp  = (bf16*) alloc((size_t)NL*DBCW*DI*2);
  bf16*  wb_dt  = (bf16*) alloc((size_t)NL*DI*DD*2);
  bf16*  wb_out = (bf16*) alloc((size_t)NL*DM*DI*2);
  bf16*  xn     = (bf16*) alloc((size_t)MROWS*DM*2);
  float* xzb    = (float*)alloc((size_t)MROWS*2*DI*4);
  float* xcf    = (float*)alloc((size_t)MROWS*DI*4);
  bf16*  xcb    = (bf16*) alloc((size_t)MROWS*DI*2);
  float* dbcf   = (float*)alloc((size_t)MROWS*DBCW*4);
  bf16*  dbcb   = (bf16*) alloc((size_t)MROWS*DBCW*2);
  float* dlt    = (float*)alloc((size_t)MROWS*DI*4);
  bf16*  scb    = (bf16*) alloc((size_t)MROWS*DI*2);
  float* x1     = (float*)alloc((size_t)MROWS*DM*4);
  float* Pws    = (float*)alloc((size_t)BB*NC*DI*DS*4);
  float* Hws    = (float*)alloc((size_t)BB*NC*DI*DS*4);

  // weights -> bf16 (once per launch; inputs restored before every call)
  f2b_kernel<<<(NL*2*DI*DM + 255)/256, 256, 0, stream>>>(w_inp,  wb_in,  NL*2*DI*DM);
  f2b_kernel<<<(NL*DBCW*DI + 255)/256, 256, 0, stream>>>(w_xprj, wb_xp,  NL*DBCW*DI);
  f2b_kernel<<<(NL*DI*DD   + 255)/256, 256, 0, stream>>>(w_dtp,  wb_dt,  NL*DI*DD);
  f2b_kernel<<<(NL*DM*DI   + 255)/256, 256, 0, stream>>>(w_outp, wb_out, NL*DM*DI);

  const float* xprev = x_in;
  for (int l = 0; l < NL; ++l) {
    rmsnorm_kernel<<<MROWS, 256, 0, stream>>>(xprev, w_norm + l*DM, xn);

    // xz = xn @ in_proj^T : [2048, 3072]
    gemm_bt<0><<<dim3(MROWS/64, (2*DI)/64), 256, 0, stream>>>(
        xn, DM, wb_in + (size_t)l*2*DI*DM, DM, xzb, 2*DI, 2*DI, DM, nullptr, nullptr);

    conv_silu_kernel<<<(MROWS*DI)/256, 256, 0, stream>>>(
        xzb, w_conv + l*DI*DCONV, b_conv + l*DI, xcf, xcb);

    // dbc = xi_conv @ xproj^T : [2048, 80]
    gemm_bt<0><<<dim3(MROWS/64, 2), 256, 0, stream>>>(
        xcb, DI, wb_xp + (size_t)l*DBCW*DI, DI, dbcf, DBCW, DBCW, DI, nullptr, nullptr);

    f2b_kernel<<<(MROWS*DBCW + 255)/256, 256, 0, stream>>>(dbcf, dbcb, MROWS*DBCW);

    // delta = softplus(dbc[:, :48] @ dt_w^T + dt_b) : [2048, 1536]
    gemm_bt<2><<<dim3(MROWS/64, DI/64), 256, 0, stream>>>(
        dbcb, DBCW, wb_dt + (size_t)l*DI*DD, DD, dlt, DI, DI, DD, b_dt + l*DI, nullptr);

    // chunked parallel scan
    scan_pass1<<<(BB*NC*DI)/16, 256, 0, stream>>>(
        dlt, xcf, dbcf, a_log + (size_t)l*DI*DS, Pws, Hws);
    scan_fix<<<(BB*DI*DS)/256, 256, 0, stream>>>(Pws, Hws);
    scan_pass2<<<(BB*NC*DI)/16, 256, 0, stream>>>(
        dlt, xcf, dbcf, a_log + (size_t)l*DI*DS, Hws, d_par + l*DI, xzb, scb);

    // x_next = x_prev + (scan_out) @ out_proj^T : [2048, 768]
    float* xout = (l == NL-1) ? xfinal : x1;
    gemm_bt<3><<<dim3(MROWS/64, DM/64), 256, 0, stream>>>(
        scb, DI, wb_out + (size_t)l*DM*DI, DI, xout, DM, DM, DI, nullptr, xprev);

    xprev = x1;
  }
}

// Round 3
// 468.207 us; speedup vs baseline: 2.3405x; 1.2170x over previous
//
#include <hip/hip_runtime.h>
#include <hip/hip_bf16.h>
#include <cstdint>

#define NL 2
#define DM 768
#define DI 1536
#define DS 16
#define DD 48
#define DCONV 4
#define BB 2
#define LL 1024
#define MROWS (BB*LL)    // 2048
#define DBCW (DD + 2*DS) // 80
#define TC 32            // scan chunk length
#define NC (LL/TC)       // 32 chunks

typedef __bf16 bf16x8 __attribute__((ext_vector_type(8)));
typedef float f32x4 __attribute__((ext_vector_type(4)));
using bf16 = __hip_bfloat16;

__device__ __forceinline__ float softplusf(float x) {
  return (x > 20.f) ? x : log1pf(__expf(x));
}

__device__ __forceinline__ void load_lds16(const void* g, void* l) {
  __builtin_amdgcn_global_load_lds(
      (const __attribute__((address_space(1))) void*)g,
      (__attribute__((address_space(3))) void*)l, 16, 0, 0);
}

// ---------------------------------------------------------------------------
// fp32 -> bf16 elementwise convert
// ---------------------------------------------------------------------------
__global__ __launch_bounds__(256)
void f2b_kernel(const float* __restrict__ in, bf16* __restrict__ out, int n)
{
  int i = blockIdx.x * 256 + threadIdx.x;
  if (i < n) out[i] = __float2bfloat16(in[i]);
}

// ---------------------------------------------------------------------------
// RMSNorm: one block per row of 768, output bf16
// ---------------------------------------------------------------------------
__global__ __launch_bounds__(256)
void rmsnorm_kernel(const float* __restrict__ x, const float* __restrict__ w,
                    bf16* __restrict__ out)
{
  const int row = blockIdx.x;
  const float* xr = x + (size_t)row * DM;
  const int t = threadIdx.x;
  float v0 = xr[t], v1 = xr[t + 256], v2 = xr[t + 512];
  float ss = v0*v0 + v1*v1 + v2*v2;
  #pragma unroll
  for (int off = 32; off > 0; off >>= 1) ss += __shfl_down(ss, off);
  __shared__ float sred[4];
  if ((t & 63) == 0) sred[t >> 6] = ss;
  __syncthreads();
  const float scale = rsqrtf((sred[0]+sred[1]+sred[2]+sred[3]) * (1.f/DM) + 1e-5f);
  out[(size_t)row*DM + t      ] = __float2bfloat16(v0 * scale * w[t]);
  out[(size_t)row*DM + t + 256] = __float2bfloat16(v1 * scale * w[t + 256]);
  out[(size_t)row*DM + t + 512] = __float2bfloat16(v2 * scale * w[t + 512]);
}

// ---------------------------------------------------------------------------
// Causal depthwise conv (K=4) + SiLU, reads xi = xz[:, 0:DI] -> bf16
// ---------------------------------------------------------------------------
__global__ __launch_bounds__(256)
void conv_silu_kernel(const float* __restrict__ xz, const float* __restrict__ cw,
                      const float* __restrict__ cb, bf16* __restrict__ xob)
{
  const int idx = blockIdx.x * 256 + threadIdx.x;   // over MROWS*DI
  const int d = idx % DI;
  const int row = idx / DI;   // b*LL + l
  const int l = row % LL;
  float acc = cb[d];
  #pragma unroll
  for (int k = 0; k < DCONV; ++k) {
    int ll = l - (DCONV-1) + k;
    if (ll >= 0)
      acc += cw[d*DCONV + k] * xz[(size_t)(row - (DCONV-1) + k) * (2*DI) + d];
  }
  const float s = acc / (1.f + __expf(-acc));
  xob[idx] = __float2bfloat16(s);
}

// ---------------------------------------------------------------------------
// 64x64 guarded bf16 MFMA GEMM (for ragged shapes: N=80, K=48)
// MODE 0: plain fp32 store
// MODE 2: C = softplus(acc + bias[col])
// ---------------------------------------------------------------------------
template<int MODE>
__global__ __launch_bounds__(256)
void gemm_bt(const bf16* __restrict__ A, int lda,
             const bf16* __restrict__ W, int ldw,
             float* __restrict__ C, int ldc,
             int N, int K,
             const float* __restrict__ bias)
{
  __shared__ __align__(16) bf16 As[64][40];
  __shared__ __align__(16) bf16 Ws[64][40];
  const int tid = threadIdx.x;
  const int m0 = blockIdx.x * 64;
  const int n0 = blockIdx.y * 64;
  const int wave = tid >> 6;
  const int lane = tid & 63;
  const int wr = (wave >> 1) * 32;
  const int wc = (wave & 1) * 32;
  const int l16 = lane & 15;
  const int quad = lane >> 4;
  const int srow = tid >> 2;         // 0..63
  const int scol = (tid & 3) * 8;    // 0,8,16,24

  f32x4 acc[2][2] = {};

  for (int k0 = 0; k0 < K; k0 += 32) {
    {
      const bf16* src = A + (size_t)(m0 + srow) * lda + (k0 + scol);
      bf16* dst = &As[srow][scol];
      if (k0 + scol + 8 <= K) {
        *reinterpret_cast<uint4*>(dst) = *reinterpret_cast<const uint4*>(src);
      } else {
        #pragma unroll
        for (int j = 0; j < 8; ++j)
          dst[j] = (k0 + scol + j < K) ? src[j] : __float2bfloat16(0.f);
      }
    }
    {
      const int n = n0 + srow;
      bf16* dst = &Ws[srow][scol];
      if (n < N && (k0 + scol + 8 <= K)) {
        *reinterpret_cast<uint4*>(dst) =
            *reinterpret_cast<const uint4*>(W + (size_t)n * ldw + (k0 + scol));
      } else {
        #pragma unroll
        for (int j = 0; j < 8; ++j)
          dst[j] = (n < N && (k0 + scol + j) < K)
                   ? W[(size_t)n * ldw + k0 + scol + j] : __float2bfloat16(0.f);
      }
    }
    __syncthreads();

    bf16x8 af[2], wf[2];
    #pragma unroll
    for (int i = 0; i < 2; ++i)
      af[i] = *reinterpret_cast<const bf16x8*>(&As[wr + i*16 + l16][quad*8]);
    #pragma unroll
    for (int j = 0; j < 2; ++j)
      wf[j] = *reinterpret_cast<const bf16x8*>(&Ws[wc + j*16 + l16][quad*8]);
    #pragma unroll
    for (int i = 0; i < 2; ++i)
      #pragma unroll
      for (int j = 0; j < 2; ++j)
        acc[i][j] = __builtin_amdgcn_mfma_f32_16x16x32_bf16(af[i], wf[j], acc[i][j], 0, 0, 0);
    __syncthreads();
  }

  #pragma unroll
  for (int i = 0; i < 2; ++i) {
    #pragma unroll
    for (int j = 0; j < 2; ++j) {
      const int col = n0 + wc + j*16 + l16;
      if (col >= N) continue;
      #pragma unroll
      for (int r = 0; r < 4; ++r) {
        const int row = m0 + wr + i*16 + quad*4 + r;
        float v = acc[i][j][r];
        const size_t idx = (size_t)row * ldc + col;
        if (MODE == 2) v = softplusf(v + bias[col]);
        C[idx] = v;
      }
    }
  }
}

// ---------------------------------------------------------------------------
// 128x128 bf16 MFMA GEMM with global_load_lds (m97 structure).
// Requires M%128==0, N%128==0, K%32==0. 4 waves, each a 64x64 quadrant
// (4x4 MFMA 16x16x32). LDS unpadded (global_load_lds lane-order constraint).
// MODE 0: plain store   MODE 3: C = acc + res[idx]
// ---------------------------------------------------------------------------
template<int MODE>
__global__ __launch_bounds__(256)
void gemm_bt128(const bf16* __restrict__ A, int lda,
                const bf16* __restrict__ W, int ldw,
                float* __restrict__ C, int ldc, int K,
                const float* __restrict__ res)
{
  __shared__ __align__(16) bf16 As[128][32];
  __shared__ __align__(16) bf16 Ws[128][32];
  const int tid = threadIdx.x;
  const int wave = tid >> 6, lane = tid & 63;
  const int m0 = blockIdx.x * 128, n0 = blockIdx.y * 128;
  const int wr = (wave >> 1) * 64, wc = (wave & 1) * 64;
  const int l16 = lane & 15, quad = lane >> 4;
  const int srow = wave * 16 + (lane >> 2);   // row this lane stages
  const int scol = (lane & 3) * 8;
  bf16* a_base0 = &As[wave*16][0];            // wave-uniform LDS dests
  bf16* a_base1 = &As[64 + wave*16][0];
  bf16* w_base0 = &Ws[wave*16][0];
  bf16* w_base1 = &Ws[64 + wave*16][0];

  f32x4 acc[4][4] = {};

  for (int k0 = 0; k0 < K; k0 += 32) {
    load_lds16(A + (size_t)(m0 + srow) * lda + k0 + scol,      a_base0);
    load_lds16(A + (size_t)(m0 + 64 + srow) * lda + k0 + scol, a_base1);
    load_lds16(W + (size_t)(n0 + srow) * ldw + k0 + scol,      w_base0);
    load_lds16(W + (size_t)(n0 + 64 + srow) * ldw + k0 + scol, w_base1);
    __syncthreads();

    bf16x8 af[4], wf[4];
    #pragma unroll
    for (int i = 0; i < 4; ++i)
      af[i] = *reinterpret_cast<const bf16x8*>(&As[wr + i*16 + l16][quad*8]);
    #pragma unroll
    for (int j = 0; j < 4; ++j)
      wf[j] = *reinterpret_cast<const bf16x8*>(&Ws[wc + j*16 + l16][quad*8]);
    #pragma unroll
    for (int i = 0; i < 4; ++i)
      #pragma unroll
      for (int j = 0; j < 4; ++j)
        acc[i][j] = __builtin_amdgcn_mfma_f32_16x16x32_bf16(af[i], wf[j], acc[i][j], 0, 0, 0);
    __syncthreads();
  }

  #pragma unroll
  for (int i = 0; i < 4; ++i) {
    #pragma unroll
    for (int j = 0; j < 4; ++j) {
      const int col = n0 + wc + j*16 + l16;
      #pragma unroll
      for (int r = 0; r < 4; ++r) {
        const int row = m0 + wr + i*16 + quad*4 + r;
        float v = acc[i][j][r];
        const size_t idx = (size_t)row * ldc + col;
        if (MODE == 3) v += res[idx];
        C[idx] = v;
      }
    }
  }
}

// ---------------------------------------------------------------------------
// Chunked parallel scan, register-state version.
// Lane owns (b, d, chunk) and 8 of the 16 n-states; partner lane (lane^32)
// owns the other 8. B/C rows staged in LDS (shared across all d).
// Layout of P/H: [b][c][d][n] (n fastest).
// ---------------------------------------------------------------------------
__global__ __launch_bounds__(256)
void scan_pass1(const float* __restrict__ delta, const bf16* __restrict__ xi,
                const float* __restrict__ dbc, const float* __restrict__ A_log,
                float* __restrict__ P, float* __restrict__ H)
{
  __shared__ float Bs[TC][DS];
  const int tid = threadIdx.x;
  const int wave = tid >> 6, lane = tid & 63;
  const int s = lane >> 5;                    // n-half: 0 -> n 0..7, 1 -> 8..15
  const int dloc = wave*32 + (lane & 31);
  const int dt = blockIdx.x % (DI/128);
  const int c  = (blockIdx.x / (DI/128)) % NC;
  const int b  =  blockIdx.x / ((DI/128)*NC);
  const int d  = dt*128 + dloc;
  const int t0 = c*TC;

  { // stage B tile [TC][16]
    const int t = tid >> 4, n = tid & 15;
    Bs[t][n]      = dbc[((size_t)b*LL + t0 + t)*DBCW + DD + n];
    Bs[t + 16][n] = dbc[((size_t)b*LL + t0 + 16 + t)*DBCW + DD + n];
  }
  float An[8];
  {
    const float4* ap = (const float4*)(A_log + (size_t)d*DS + s*8);
    float4 v0 = ap[0], v1 = ap[1];
    An[0] = -__expf(v0.x)*1.44269504f; An[1] = -__expf(v0.y)*1.44269504f;
    An[2] = -__expf(v0.z)*1.44269504f; An[3] = -__expf(v0.w)*1.44269504f;
    An[4] = -__expf(v1.x)*1.44269504f; An[5] = -__expf(v1.y)*1.44269504f;
    An[6] = -__expf(v1.z)*1.44269504f; An[7] = -__expf(v1.w)*1.44269504f;
  }
  __syncthreads();

  const float* dptr = delta + ((size_t)b*LL + t0)*DI + d;
  const bf16*  xptr = xi    + ((size_t)b*LL + t0)*DI + d;
  float h[8] = {0.f,0.f,0.f,0.f,0.f,0.f,0.f,0.f};
  float sdl = 0.f;
  #pragma unroll
  for (int t = 0; t < TC; ++t) {
    const float dl = dptr[(size_t)t*DI];
    const float xv = __bfloat162float(xptr[(size_t)t*DI]);
    const float dlxv = dl * xv;
    sdl += dl;
    const float4* brow = (const float4*)&Bs[t][s*8];
    const float4 b0 = brow[0], b1 = brow[1];
    const float bb[8] = {b0.x,b0.y,b0.z,b0.w,b1.x,b1.y,b1.z,b1.w};
    #pragma unroll
    for (int n = 0; n < 8; ++n) {
      const float dA = exp2f(dl * An[n]);
      h[n] = dA*h[n] + dlxv*bb[n];
    }
  }
  const size_t base = (((size_t)b*NC + c)*DI + d)*DS + s*8;
  float4* Pp = (float4*)(P + base);
  float4* Hp = (float4*)(H + base);
  Pp[0] = make_float4(exp2f(An[0]*sdl), exp2f(An[1]*sdl), exp2f(An[2]*sdl), exp2f(An[3]*sdl));
  Pp[1] = make_float4(exp2f(An[4]*sdl), exp2f(An[5]*sdl), exp2f(An[6]*sdl), exp2f(An[7]*sdl));
  Hp[0] = make_float4(h[0],h[1],h[2],h[3]);
  Hp[1] = make_float4(h[4],h[5],h[6],h[7]);
}

__global__ __launch_bounds__(256)
void scan_fix(const float* __restrict__ P, float* __restrict__ H)
{
  const int idx = blockIdx.x * 256 + threadIdx.x;   // over BB*DI*DS
  const int n = idx & 15;
  const int d = (idx >> 4) % DI;
  const int b = idx / (DS * DI);
  float hin = 0.f;
  #pragma unroll 8
  for (int c = 0; c < NC; ++c) {
    const size_t ic = (((size_t)b*NC + c)*DI + d)*DS + n;
    const float Pv = P[ic];
    const float Hv = H[ic];
    H[ic] = hin;
    hin = fmaf(Pv, hin, Hv);
  }
}

__global__ __launch_bounds__(256)
void scan_pass2(const float* __restrict__ delta, const bf16* __restrict__ xi,
                const float* __restrict__ dbc, const float* __restrict__ A_log,
                const float* __restrict__ H, const float* __restrict__ Dp,
                const float* __restrict__ xz, bf16* __restrict__ outb)
{
  __shared__ float Bs[TC][DS];
  __shared__ float Cs[TC][DS];
  const int tid = threadIdx.x;
  const int wave = tid >> 6, lane = tid & 63;
  const int s = lane >> 5;
  const int dloc = wave*32 + (lane & 31);
  const int dt = blockIdx.x % (DI/128);
  const int c  = (blockIdx.x / (DI/128)) % NC;
  const int b  =  blockIdx.x / ((DI/128)*NC);
  const int d  = dt*128 + dloc;
  const int t0 = c*TC;

  {
    const int t = tid >> 4, n = tid & 15;
    const size_t r0 = ((size_t)b*LL + t0 + t)*DBCW;
    const size_t r1 = ((size_t)b*LL + t0 + 16 + t)*DBCW;
    Bs[t][n]      = dbc[r0 + DD + n];
    Bs[t + 16][n] = dbc[r1 + DD + n];
    Cs[t][n]      = dbc[r0 + DD + DS + n];
    Cs[t + 16][n] = dbc[r1 + DD + DS + n];
  }
  float An[8];
  {
    const float4* ap = (const float4*)(A_log + (size_t)d*DS + s*8);
    float4 v0 = ap[0], v1 = ap[1];
    An[0] = -__expf(v0.x)*1.44269504f; An[1] = -__expf(v0.y)*1.44269504f;
    An[2] = -__expf(v0.z)*1.44269504f; An[3] = -__expf(v0.w)*1.44269504f;
    An[4] = -__expf(v1.x)*1.44269504f; An[5] = -__expf(v1.y)*1.44269504f;
    An[6] = -__expf(v1.z)*1.44269504f; An[7] = -__expf(v1.w)*1.44269504f;
  }
  const float Dd = Dp[d];
  float h[8];
  {
    const float4* hp = (const float4*)(H + (((size_t)b*NC + c)*DI + d)*DS + s*8);
    float4 h0 = hp[0], h1 = hp[1];
    h[0]=h0.x; h[1]=h0.y; h[2]=h0.z; h[3]=h0.w;
    h[4]=h1.x; h[5]=h1.y; h[6]=h1.z; h[7]=h1.w;
  }
  __syncthreads();

  const float* dptr = delta + ((size_t)b*LL + t0)*DI + d;
  const bf16*  xptr = xi    + ((size_t)b*LL + t0)*DI + d;
  const float* zptr = xz    + ((size_t)b*LL + t0)*(2*DI) + DI + d;
  bf16* optr = outb + ((size_t)b*LL + t0)*DI + d;

  #pragma unroll
  for (int t = 0; t < TC; ++t) {
    const float dl = dptr[(size_t)t*DI];
    const float xv = __bfloat162float(xptr[(size_t)t*DI]);
    const float zv = zptr[(size_t)t*(2*DI)];
    const float dlxv = dl * xv;
    const float4* brow = (const float4*)&Bs[t][s*8];
    const float4* crow = (const float4*)&Cs[t][s*8];
    const float4 b0 = brow[0], b1 = brow[1];
    const float4 c0 = crow[0], c1 = crow[1];
    const float bb[8] = {b0.x,b0.y,b0.z,b0.w,b1.x,b1.y,b1.z,b1.w};
    const float cc[8] = {c0.x,c0.y,c0.z,c0.w,c1.x,c1.y,c1.z,c1.w};
    float y = 0.f;
    #pragma unroll
    for (int n = 0; n < 8; ++n) {
      const float dA = exp2f(dl * An[n]);
      h[n] = dA*h[n] + dlxv*bb[n];
      y = fmaf(h[n], cc[n], y);
    }
    y += __shfl_xor(y, 32);
    if (s == 0) {
      const float o = (y + Dd * xv) * (zv / (1.f + __expf(-zv)));
      optr[(size_t)t*DI] = __float2bfloat16(o);
    }
  }
}

// ---------------------------------------------------------------------------
extern "C" void kernel_launch(void* const* d_in, const int* in_sizes, int n_in,
                              void* d_out, int out_size, void* d_ws, size_t ws_size,
                              hipStream_t stream)
{
  const float* x_in   = (const float*)d_in[0];
  const float* w_inp  = (const float*)d_in[1];
  const float* w_conv = (const float*)d_in[2];
  const float* b_conv = (const float*)d_in[3];
  const float* w_xprj = (const float*)d_in[4];
  const float* w_dtp  = (const float*)d_in[5];
  const float* b_dt   = (const float*)d_in[6];
  const float* a_log  = (const float*)d_in[7];
  const float* d_par  = (const float*)d_in[8];
  const float* w_outp = (const float*)d_in[9];
  const float* w_norm = (const float*)d_in[10];
  float* xfinal = (float*)d_out;

  char* ws = (char*)d_ws;
  size_t off = 0;
  auto alloc = [&](size_t bytes) -> void* {
    void* p = ws + off;
    off += (bytes + 255) & ~(size_t)255;
    return p;
  };
  bf16*  wb_in  = (bf16*) alloc((size_t)NL*2*DI*DM*2);
  bf16*  wb_xp  = (bf16*) alloc((size_t)NL*DBCW*DI*2);
  bf16*  wb_dt  = (bf16*) alloc((size_t)NL*DI*DD*2);
  bf16*  wb_out = (bf16*) alloc((size_t)NL*DM*DI*2);
  bf16*  xn     = (bf16*) alloc((size_t)MROWS*DM*2);
  float* xzb    = (float*)alloc((size_t)MROWS*2*DI*4);
  bf16*  xcb    = (bf16*) alloc((size_t)MROWS*DI*2);
  float* dbcf   = (float*)alloc((size_t)MROWS*DBCW*4);
  bf16*  dbcb   = (bf16*) alloc((size_t)MROWS*DBCW*2);
  float* dlt    = (float*)alloc((size_t)MROWS*DI*4);
  bf16*  scb    = (bf16*) alloc((size_t)MROWS*DI*2);
  float* x1     = (float*)alloc((size_t)MROWS*DM*4);
  float* Pws    = (float*)alloc((size_t)BB*NC*DI*DS*4);
  float* Hws    = (float*)alloc((size_t)BB*NC*DI*DS*4);

  // weights -> bf16 (once per launch; inputs restored before every call)
  f2b_kernel<<<(NL*2*DI*DM + 255)/256, 256, 0, stream>>>(w_inp,  wb_in,  NL*2*DI*DM);
  f2b_kernel<<<(NL*DBCW*DI + 255)/256, 256, 0, stream>>>(w_xprj, wb_xp,  NL*DBCW*DI);
  f2b_kernel<<<(NL*DI*DD   + 255)/256, 256, 0, stream>>>(w_dtp,  wb_dt,  NL*DI*DD);
  f2b_kernel<<<(NL*DM*DI   + 255)/256, 256, 0, stream>>>(w_outp, wb_out, NL*DM*DI);

  const float* xprev = x_in;
  for (int l = 0; l < NL; ++l) {
    rmsnorm_kernel<<<MROWS, 256, 0, stream>>>(xprev, w_norm + l*DM, xn);

    // xz = xn @ in_proj^T : [2048, 3072], K=768
    gemm_bt128<0><<<dim3(MROWS/128, (2*DI)/128), 256, 0, stream>>>(
        xn, DM, wb_in + (size_t)l*2*DI*DM, DM, xzb, 2*DI, DM, nullptr);

    conv_silu_kernel<<<(MROWS*DI)/256, 256, 0, stream>>>(
        xzb, w_conv + l*DI*DCONV, b_conv + l*DI, xcb);

    // dbc = xi_conv @ xproj^T : [2048, 80], K=1536
    gemm_bt<0><<<dim3(MROWS/64, 2), 256, 0, stream>>>(
        xcb, DI, wb_xp + (size_t)l*DBCW*DI, DI, dbcf, DBCW, DBCW, DI, nullptr);

    f2b_kernel<<<(MROWS*DBCW + 255)/256, 256, 0, stream>>>(dbcf, dbcb, MROWS*DBCW);

    // delta = softplus(dbc[:, :48] @ dt_w^T + dt_b) : [2048, 1536], K=48
    gemm_bt<2><<<dim3(MROWS/64, DI/64), 256, 0, stream>>>(
        dbcb, DBCW, wb_dt + (size_t)l*DI*DD, DD, dlt, DI, DI, DD, b_dt + l*DI);

    // chunked parallel scan
    scan_pass1<<<BB*NC*(DI/128), 256, 0, stream>>>(
        dlt, xcb, dbcf, a_log + (size_t)l*DI*DS, Pws, Hws);
    scan_fix<<<(BB*DI*DS)/256, 256, 0, stream>>>(Pws, Hws);
    scan_pass2<<<BB*NC*(DI/128), 256, 0, stream>>>(
        dlt, xcb, dbcf, a_log + (size_t)l*DI*DS, Hws, d_par + l*DI, xzb, scb);

    // x_next = x_prev + (scan_out) @ out_proj^T : [2048, 768], K=1536
    float* xout = (l == NL-1) ? xfinal : x1;
    gemm_bt128<3><<<dim3(MROWS/128, DM/128), 256, 0, stream>>>(
        scb, DI, wb_out + (size_t)l*DM*DI, DI, xout, DM, DI, xprev);

    xprev = x1;
  }
}

// Round 4
// 392.738 us; speedup vs baseline: 2.7903x; 1.1922x over previous
//
#include <hip/hip_runtime.h>
#include <hip/hip_bf16.h>
#include <cstdint>

#define NL 2
#define DM 768
#define DI 1536
#define DS 16
#define DD 48
#define DCONV 4
#define BB 2
#define LL 1024
#define MROWS (BB*LL)    // 2048
#define DBCW (DD + 2*DS) // 80
#define TC 32            // scan chunk length
#define NC (LL/TC)       // 32 chunks
#define KSPL 4           // x_proj split-K ways
#define XPN 128          // x_proj padded N

typedef __bf16 bf16x8 __attribute__((ext_vector_type(8)));
typedef float f32x4 __attribute__((ext_vector_type(4)));
using bf16 = __hip_bfloat16;

__device__ __forceinline__ float softplusf(float x) {
  return (x > 20.f) ? x : log1pf(__expf(x));
}

__device__ __forceinline__ void load_lds16(const void* g, void* l) {
  __builtin_amdgcn_global_load_lds(
      (const __attribute__((address_space(1))) void*)g,
      (__attribute__((address_space(3))) void*)l, 16, 0, 0);
}

// ---------------------------------------------------------------------------
// All weight fp32->bf16 conversions in one kernel; pads x_proj N 80->128.
// ---------------------------------------------------------------------------
#define WI_N (NL*2*DI*DM)
#define WX_N (NL*XPN*DI)
#define WD_N (NL*DI*DD)
#define WO_N (NL*DM*DI)
__global__ __launch_bounds__(256)
void prep_weights(const float* __restrict__ wi, const float* __restrict__ wx,
                  const float* __restrict__ wd, const float* __restrict__ wo,
                  bf16* __restrict__ bi, bf16* __restrict__ bx,
                  bf16* __restrict__ bd, bf16* __restrict__ bo)
{
  int i = blockIdx.x * 256 + threadIdx.x;
  if (i < WI_N) { bi[i] = __float2bfloat16(wi[i]); return; }
  i -= WI_N;
  if (i < WX_N) {
    const int l = i / (XPN*DI), r = (i / DI) % XPN, k = i % DI;
    const float v = (r < DBCW) ? wx[((size_t)l*DBCW + r)*DI + k] : 0.f;
    bx[i] = __float2bfloat16(v); return;
  }
  i -= WX_N;
  if (i < WD_N) { bd[i] = __float2bfloat16(wd[i]); return; }
  i -= WD_N;
  if (i < WO_N) { bo[i] = __float2bfloat16(wo[i]); }
}

// ---------------------------------------------------------------------------
// RMSNorm: one block per row of 768, output bf16
// ---------------------------------------------------------------------------
__global__ __launch_bounds__(256)
void rmsnorm_kernel(const float* __restrict__ x, const float* __restrict__ w,
                    bf16* __restrict__ out)
{
  const int row = blockIdx.x;
  const float* xr = x + (size_t)row * DM;
  const int t = threadIdx.x;
  float v0 = xr[t], v1 = xr[t + 256], v2 = xr[t + 512];
  float ss = v0*v0 + v1*v1 + v2*v2;
  #pragma unroll
  for (int off = 32; off > 0; off >>= 1) ss += __shfl_down(ss, off);
  __shared__ float sred[4];
  if ((t & 63) == 0) sred[t >> 6] = ss;
  __syncthreads();
  const float scale = rsqrtf((sred[0]+sred[1]+sred[2]+sred[3]) * (1.f/DM) + 1e-5f);
  out[(size_t)row*DM + t      ] = __float2bfloat16(v0 * scale * w[t]);
  out[(size_t)row*DM + t + 256] = __float2bfloat16(v1 * scale * w[t + 256]);
  out[(size_t)row*DM + t + 512] = __float2bfloat16(v2 * scale * w[t + 512]);
}

// ---------------------------------------------------------------------------
// in_proj GEMM: 128x128 tile, global_load_lds. Output split:
// cols < DI -> fp32 xzf [2048][DI];  cols >= DI -> bf16 zb [2048][DI].
// ---------------------------------------------------------------------------
__global__ __launch_bounds__(256)
void gemm_in128(const bf16* __restrict__ A, const bf16* __restrict__ W,
                float* __restrict__ xzf, bf16* __restrict__ zb)
{
  __shared__ __align__(16) bf16 As[128][32];
  __shared__ __align__(16) bf16 Ws[128][32];
  const int tid = threadIdx.x;
  const int wave = tid >> 6, lane = tid & 63;
  const int m0 = blockIdx.x * 128, n0 = blockIdx.y * 128;
  const int wr = (wave >> 1) * 64, wc = (wave & 1) * 64;
  const int l16 = lane & 15, quad = lane >> 4;
  const int srow = wave * 16 + (lane >> 2);
  const int scol = (lane & 3) * 8;
  bf16* a_base0 = &As[wave*16][0];
  bf16* a_base1 = &As[64 + wave*16][0];
  bf16* w_base0 = &Ws[wave*16][0];
  bf16* w_base1 = &Ws[64 + wave*16][0];

  f32x4 acc[4][4] = {};

  for (int k0 = 0; k0 < DM; k0 += 32) {
    load_lds16(A + (size_t)(m0 + srow) * DM + k0 + scol,      a_base0);
    load_lds16(A + (size_t)(m0 + 64 + srow) * DM + k0 + scol, a_base1);
    load_lds16(W + (size_t)(n0 + srow) * DM + k0 + scol,      w_base0);
    load_lds16(W + (size_t)(n0 + 64 + srow) * DM + k0 + scol, w_base1);
    __syncthreads();

    bf16x8 af[4], wf[4];
    #pragma unroll
    for (int i = 0; i < 4; ++i)
      af[i] = *reinterpret_cast<const bf16x8*>(&As[wr + i*16 + l16][quad*8]);
    #pragma unroll
    for (int j = 0; j < 4; ++j)
      wf[j] = *reinterpret_cast<const bf16x8*>(&Ws[wc + j*16 + l16][quad*8]);
    #pragma unroll
    for (int i = 0; i < 4; ++i)
      #pragma unroll
      for (int j = 0; j < 4; ++j)
        acc[i][j] = __builtin_amdgcn_mfma_f32_16x16x32_bf16(af[i], wf[j], acc[i][j], 0, 0, 0);
    __syncthreads();
  }

  const bool isz = (n0 >= DI);
  #pragma unroll
  for (int i = 0; i < 4; ++i) {
    #pragma unroll
    for (int j = 0; j < 4; ++j) {
      const int col = n0 + wc + j*16 + l16;
      #pragma unroll
      for (int r = 0; r < 4; ++r) {
        const int row = m0 + wr + i*16 + quad*4 + r;
        const float v = acc[i][j][r];
        if (!isz) xzf[(size_t)row*DI + col] = v;
        else      zb[(size_t)row*DI + col - DI] = __float2bfloat16(v);
      }
    }
  }
}

// ---------------------------------------------------------------------------
// 64x64 tile GEMM with global_load_lds. K%32==0, staged N%64==0 (pad W).
// gridDim.z = split-K ways: block z handles K-slice [z*K,(z+1)*K) and writes
// partial z (C += z*MROWS*ldc).  MODE 0: plain fp32 partial, guard col<N.
// MODE 3: C = acc + res (full K, gridDim.z=1).
// ---------------------------------------------------------------------------
template<int MODE>
__global__ __launch_bounds__(256)
void gemm64l(const bf16* __restrict__ A, int lda,
             const bf16* __restrict__ W, int ldw,
             float* __restrict__ C, int ldc, int N, int K,
             const float* __restrict__ res)
{
  __shared__ __align__(16) bf16 As[64][32];
  __shared__ __align__(16) bf16 Ws[64][32];
  const int tid = threadIdx.x;
  const int wave = tid >> 6, lane = tid & 63;
  const int m0 = blockIdx.x * 64, n0 = blockIdx.y * 64;
  const int wr = (wave >> 1) * 32, wc = (wave & 1) * 32;
  const int l16 = lane & 15, quad = lane >> 4;
  const int srow = wave * 16 + (lane >> 2);
  const int scol = (lane & 3) * 8;
  bf16* a_base = &As[wave*16][0];
  bf16* w_base = &Ws[wave*16][0];

  A += (size_t)blockIdx.z * K;              // split-K column offset
  W += (size_t)blockIdx.z * K;
  C += (size_t)blockIdx.z * MROWS * ldc;    // partial-buffer offset

  f32x4 acc[2][2] = {};

  for (int k0 = 0; k0 < K; k0 += 32) {
    load_lds16(A + (size_t)(m0 + srow) * lda + k0 + scol, a_base);
    load_lds16(W + (size_t)(n0 + srow) * ldw + k0 + scol, w_base);
    __syncthreads();
    bf16x8 af[2], wf[2];
    #pragma unroll
    for (int i = 0; i < 2; ++i)
      af[i] = *reinterpret_cast<const bf16x8*>(&As[wr + i*16 + l16][quad*8]);
    #pragma unroll
    for (int j = 0; j < 2; ++j)
      wf[j] = *reinterpret_cast<const bf16x8*>(&Ws[wc + j*16 + l16][quad*8]);
    #pragma unroll
    for (int i = 0; i < 2; ++i)
      #pragma unroll
      for (int j = 0; j < 2; ++j)
        acc[i][j] = __builtin_amdgcn_mfma_f32_16x16x32_bf16(af[i], wf[j], acc[i][j], 0, 0, 0);
    __syncthreads();
  }

  #pragma unroll
  for (int i = 0; i < 2; ++i) {
    #pragma unroll
    for (int j = 0; j < 2; ++j) {
      const int col = n0 + wc + j*16 + l16;
      if (col >= N) continue;
      #pragma unroll
      for (int r = 0; r < 4; ++r) {
        const int row = m0 + wr + i*16 + quad*4 + r;
        float v = acc[i][j][r];
        const size_t idx = (size_t)row * ldc + col;
        if (MODE == 3) v += res[idx];
        C[idx] = v;
      }
    }
  }
}

// ---------------------------------------------------------------------------
// x_proj split-K reduce; emits bf16 delta-input block and fp32 B/C block.
// ---------------------------------------------------------------------------
__global__ __launch_bounds__(256)
void xproj_reduce(const float* __restrict__ part, bf16* __restrict__ dbcb,
                  float* __restrict__ bcf)
{
  const int idx = blockIdx.x * 256 + threadIdx.x;   // over MROWS*DBCW
  const int row = idx / DBCW, col = idx % DBCW;
  float v = part[idx];
  #pragma unroll
  for (int z = 1; z < KSPL; ++z) v += part[idx + (size_t)z*MROWS*DBCW];
  if (col < DD) dbcb[(size_t)row*DD + col] = __float2bfloat16(v);
  else          bcf[(size_t)row*32 + col - DD] = v;
}

// ---------------------------------------------------------------------------
// Causal depthwise conv (K=4) + SiLU on xzf -> bf16 xcb
// ---------------------------------------------------------------------------
__global__ __launch_bounds__(256)
void conv_silu_kernel(const float* __restrict__ xzf, const float* __restrict__ cw,
                      const float* __restrict__ cb, bf16* __restrict__ xob)
{
  const int idx = blockIdx.x * 256 + threadIdx.x;   // over MROWS*DI
  const int d = idx % DI;
  const int row = idx / DI;   // b*LL + l
  const int l = row % LL;
  float acc = cb[d];
  #pragma unroll
  for (int k = 0; k < DCONV; ++k) {
    const int ll = l - (DCONV-1) + k;
    if (ll >= 0)
      acc += cw[d*DCONV + k] * xzf[(size_t)(row - (DCONV-1) + k) * DI + d];
  }
  const float s = acc / (1.f + __expf(-acc));
  xob[idx] = __float2bfloat16(s);
}

// ---------------------------------------------------------------------------
// dt GEMM (guarded 64x64): delta = softplus(dbcb[2048x48] @ dt_w^T + b) -> bf16
// ---------------------------------------------------------------------------
__global__ __launch_bounds__(256)
void gemm_dt(const bf16* __restrict__ A, const bf16* __restrict__ W,
             bf16* __restrict__ Cb, const float* __restrict__ bias)
{
  __shared__ __align__(16) bf16 As[64][40];
  __shared__ __align__(16) bf16 Ws[64][40];
  const int tid = threadIdx.x;
  const int m0 = blockIdx.x * 64, n0 = blockIdx.y * 64;
  const int wave = tid >> 6, lane = tid & 63;
  const int wr = (wave >> 1) * 32, wc = (wave & 1) * 32;
  const int l16 = lane & 15, quad = lane >> 4;
  const int srow = tid >> 2;
  const int scol = (tid & 3) * 8;

  f32x4 acc[2][2] = {};

  #pragma unroll
  for (int k0 = 0; k0 < DD; k0 += 32) {
    {
      const bf16* src = A + (size_t)(m0 + srow) * DD + (k0 + scol);
      bf16* dst = &As[srow][scol];
      if (k0 + scol + 8 <= DD) {
        *reinterpret_cast<uint4*>(dst) = *reinterpret_cast<const uint4*>(src);
      } else {
        #pragma unroll
        for (int j = 0; j < 8; ++j)
          dst[j] = (k0 + scol + j < DD) ? src[j] : __float2bfloat16(0.f);
      }
    }
    {
      const bf16* src = W + (size_t)(n0 + srow) * DD + (k0 + scol);
      bf16* dst = &Ws[srow][scol];
      if (k0 + scol + 8 <= DD) {
        *reinterpret_cast<uint4*>(dst) = *reinterpret_cast<const uint4*>(src);
      } else {
        #pragma unroll
        for (int j = 0; j < 8; ++j)
          dst[j] = (k0 + scol + j < DD) ? src[j] : __float2bfloat16(0.f);
      }
    }
    __syncthreads();
    bf16x8 af[2], wf[2];
    #pragma unroll
    for (int i = 0; i < 2; ++i)
      af[i] = *reinterpret_cast<const bf16x8*>(&As[wr + i*16 + l16][quad*8]);
    #pragma unroll
    for (int j = 0; j < 2; ++j)
      wf[j] = *reinterpret_cast<const bf16x8*>(&Ws[wc + j*16 + l16][quad*8]);
    #pragma unroll
    for (int i = 0; i < 2; ++i)
      #pragma unroll
      for (int j = 0; j < 2; ++j)
        acc[i][j] = __builtin_amdgcn_mfma_f32_16x16x32_bf16(af[i], wf[j], acc[i][j], 0, 0, 0);
    __syncthreads();
  }

  #pragma unroll
  for (int i = 0; i < 2; ++i) {
    #pragma unroll
    for (int j = 0; j < 2; ++j) {
      const int col = n0 + wc + j*16 + l16;
      #pragma unroll
      for (int r = 0; r < 4; ++r) {
        const int row = m0 + wr + i*16 + quad*4 + r;
        Cb[(size_t)row*DI + col] = __float2bfloat16(softplusf(acc[i][j][r] + bias[col]));
      }
    }
  }
}

// ---------------------------------------------------------------------------
// Chunked parallel scan (register-state). Lane owns (b,d,chunk) and 8 of the
// 16 n-states; partner lane (lane^32) the other 8. B/C staged in LDS.
// P/H layout: [b][c][d][n].
// ---------------------------------------------------------------------------
__global__ __launch_bounds__(256)
void scan_pass1(const bf16* __restrict__ delta, const bf16* __restrict__ xi,
                const float* __restrict__ bcf, const float* __restrict__ A_log,
                float* __restrict__ P, float* __restrict__ H)
{
  __shared__ float Bs[TC][DS];
  const int tid = threadIdx.x;
  const int wave = tid >> 6, lane = tid & 63;
  const int s = lane >> 5;
  const int dloc = wave*32 + (lane & 31);
  const int dt = blockIdx.x % (DI/128);
  const int c  = (blockIdx.x / (DI/128)) % NC;
  const int b  =  blockIdx.x / ((DI/128)*NC);
  const int d  = dt*128 + dloc;
  const int t0 = c*TC;

  { // stage B tile [TC][16]
    const int t = tid >> 4, n = tid & 15;
    Bs[t][n]      = bcf[((size_t)b*LL + t0 + t)*32 + n];
    Bs[t + 16][n] = bcf[((size_t)b*LL + t0 + 16 + t)*32 + n];
  }
  float An[8];
  {
    const float4* ap = (const float4*)(A_log + (size_t)d*DS + s*8);
    float4 v0 = ap[0], v1 = ap[1];
    An[0] = -__expf(v0.x)*1.44269504f; An[1] = -__expf(v0.y)*1.44269504f;
    An[2] = -__expf(v0.z)*1.44269504f; An[3] = -__expf(v0.w)*1.44269504f;
    An[4] = -__expf(v1.x)*1.44269504f; An[5] = -__expf(v1.y)*1.44269504f;
    An[6] = -__expf(v1.z)*1.44269504f; An[7] = -__expf(v1.w)*1.44269504f;
  }
  __syncthreads();

  const bf16* dptr = delta + ((size_t)b*LL + t0)*DI + d;
  const bf16* xptr = xi    + ((size_t)b*LL + t0)*DI + d;
  float h[8] = {0.f,0.f,0.f,0.f,0.f,0.f,0.f,0.f};
  float sdl = 0.f;
  #pragma unroll
  for (int t = 0; t < TC; ++t) {
    const float dl = __bfloat162float(dptr[(size_t)t*DI]);
    const float xv = __bfloat162float(xptr[(size_t)t*DI]);
    const float dlxv = dl * xv;
    sdl += dl;
    const float4* brow = (const float4*)&Bs[t][s*8];
    const float4 b0 = brow[0], b1 = brow[1];
    const float bb[8] = {b0.x,b0.y,b0.z,b0.w,b1.x,b1.y,b1.z,b1.w};
    #pragma unroll
    for (int n = 0; n < 8; ++n) {
      const float dA = exp2f(dl * An[n]);
      h[n] = dA*h[n] + dlxv*bb[n];
    }
  }
  const size_t base = (((size_t)b*NC + c)*DI + d)*DS + s*8;
  float4* Pp = (float4*)(P + base);
  float4* Hp = (float4*)(H + base);
  Pp[0] = make_float4(exp2f(An[0]*sdl), exp2f(An[1]*sdl), exp2f(An[2]*sdl), exp2f(An[3]*sdl));
  Pp[1] = make_float4(exp2f(An[4]*sdl), exp2f(An[5]*sdl), exp2f(An[6]*sdl), exp2f(An[7]*sdl));
  Hp[0] = make_float4(h[0],h[1],h[2],h[3]);
  Hp[1] = make_float4(h[4],h[5],h[6],h[7]);
}

__global__ __launch_bounds__(256)
void scan_fix(const float* __restrict__ P, float* __restrict__ H)
{
  const int idx = blockIdx.x * 256 + threadIdx.x;   // over BB*DI*DS
  const int n = idx & 15;
  const int d = (idx >> 4) % DI;
  const int b = idx / (DS * DI);
  float hin = 0.f;
  #pragma unroll 8
  for (int c = 0; c < NC; ++c) {
    const size_t ic = (((size_t)b*NC + c)*DI + d)*DS + n;
    const float Pv = P[ic];
    const float Hv = H[ic];
    H[ic] = hin;
    hin = fmaf(Pv, hin, Hv);
  }
}

__global__ __launch_bounds__(256)
void scan_pass2(const bf16* __restrict__ delta, const bf16* __restrict__ xi,
                const float* __restrict__ bcf, const float* __restrict__ A_log,
                const float* __restrict__ H, const float* __restrict__ Dp,
                const bf16* __restrict__ zb, bf16* __restrict__ outb)
{
  __shared__ float Bs[TC][DS];
  __shared__ float Cs[TC][DS];
  const int tid = threadIdx.x;
  const int wave = tid >> 6, lane = tid & 63;
  const int s = lane >> 5;
  const int dloc = wave*32 + (lane & 31);
  const int dt = blockIdx.x % (DI/128);
  const int c  = (blockIdx.x / (DI/128)) % NC;
  const int b  =  blockIdx.x / ((DI/128)*NC);
  const int d  = dt*128 + dloc;
  const int t0 = c*TC;

  {
    const int t = tid >> 4, n = tid & 15;
    const size_t r0 = ((size_t)b*LL + t0 + t)*32;
    const size_t r1 = ((size_t)b*LL + t0 + 16 + t)*32;
    Bs[t][n]      = bcf[r0 + n];
    Bs[t + 16][n] = bcf[r1 + n];
    Cs[t][n]      = bcf[r0 + 16 + n];
    Cs[t + 16][n] = bcf[r1 + 16 + n];
  }
  float An[8];
  {
    const float4* ap = (const float4*)(A_log + (size_t)d*DS + s*8);
    float4 v0 = ap[0], v1 = ap[1];
    An[0] = -__expf(v0.x)*1.44269504f; An[1] = -__expf(v0.y)*1.44269504f;
    An[2] = -__expf(v0.z)*1.44269504f; An[3] = -__expf(v0.w)*1.44269504f;
    An[4] = -__expf(v1.x)*1.44269504f; An[5] = -__expf(v1.y)*1.44269504f;
    An[6] = -__expf(v1.z)*1.44269504f; An[7] = -__expf(v1.w)*1.44269504f;
  }
  const float Dd = Dp[d];
  float h[8];
  {
    const float4* hp = (const float4*)(H + (((size_t)b*NC + c)*DI + d)*DS + s*8);
    float4 h0 = hp[0], h1 = hp[1];
    h[0]=h0.x; h[1]=h0.y; h[2]=h0.z; h[3]=h0.w;
    h[4]=h1.x; h[5]=h1.y; h[6]=h1.z; h[7]=h1.w;
  }
  __syncthreads();

  const bf16* dptr = delta + ((size_t)b*LL + t0)*DI + d;
  const bf16* xptr = xi    + ((size_t)b*LL + t0)*DI + d;
  const bf16* zptr = zb    + ((size_t)b*LL + t0)*DI + d;
  bf16* optr = outb + ((size_t)b*LL + t0)*DI + d;

  #pragma unroll
  for (int t = 0; t < TC; ++t) {
    const float dl = __bfloat162float(dptr[(size_t)t*DI]);
    const float xv = __bfloat162float(xptr[(size_t)t*DI]);
    const float zv = __bfloat162float(zptr[(size_t)t*DI]);
    const float dlxv = dl * xv;
    const float4* brow = (const float4*)&Bs[t][s*8];
    const float4* crow = (const float4*)&Cs[t][s*8];
    const float4 b0 = brow[0], b1 = brow[1];
    const float4 c0 = crow[0], c1 = crow[1];
    const float bb[8] = {b0.x,b0.y,b0.z,b0.w,b1.x,b1.y,b1.z,b1.w};
    const float cc[8] = {c0.x,c0.y,c0.z,c0.w,c1.x,c1.y,c1.z,c1.w};
    float y = 0.f;
    #pragma unroll
    for (int n = 0; n < 8; ++n) {
      const float dA = exp2f(dl * An[n]);
      h[n] = dA*h[n] + dlxv*bb[n];
      y = fmaf(h[n], cc[n], y);
    }
    y += __shfl_xor(y, 32);
    if (s == 0) {
      const float o = (y + Dd * xv) * (zv / (1.f + __expf(-zv)));
      optr[(size_t)t*DI] = __float2bfloat16(o);
    }
  }
}

// ---------------------------------------------------------------------------
extern "C" void kernel_launch(void* const* d_in, const int* in_sizes, int n_in,
                              void* d_out, int out_size, void* d_ws, size_t ws_size,
                              hipStream_t stream)
{
  const float* x_in   = (const float*)d_in[0];
  const float* w_inp  = (const float*)d_in[1];
  const float* w_conv = (const float*)d_in[2];
  const float* b_conv = (const float*)d_in[3];
  const float* w_xprj = (const float*)d_in[4];
  const float* w_dtp  = (const float*)d_in[5];
  const float* b_dt   = (const float*)d_in[6];
  const float* a_log  = (const float*)d_in[7];
  const float* d_par  = (const float*)d_in[8];
  const float* w_outp = (const float*)d_in[9];
  const float* w_norm = (const float*)d_in[10];
  float* xfinal = (float*)d_out;

  char* ws = (char*)d_ws;
  size_t off = 0;
  auto alloc = [&](size_t bytes) -> void* {
    void* p = ws + off;
    off += (bytes + 255) & ~(size_t)255;
    return p;
  };
  bf16*  wb_in  = (bf16*) alloc((size_t)WI_N*2);
  bf16*  wb_xp  = (bf16*) alloc((size_t)WX_N*2);
  bf16*  wb_dt  = (bf16*) alloc((size_t)WD_N*2);
  bf16*  wb_out = (bf16*) alloc((size_t)WO_N*2);
  bf16*  xn     = (bf16*) alloc((size_t)MROWS*DM*2);
  float* xzf    = (float*)alloc((size_t)MROWS*DI*4);
  bf16*  zb     = (bf16*) alloc((size_t)MROWS*DI*2);
  bf16*  xcb    = (bf16*) alloc((size_t)MROWS*DI*2);
  float* xpart  = (float*)alloc((size_t)KSPL*MROWS*DBCW*4);
  bf16*  dbcb   = (bf16*) alloc((size_t)MROWS*DD*2);
  float* bcf    = (float*)alloc((size_t)MROWS*32*4);
  bf16*  dltb   = (bf16*) alloc((size_t)MROWS*DI*2);
  bf16*  scb    = (bf16*) alloc((size_t)MROWS*DI*2);
  float* x1     = (float*)alloc((size_t)MROWS*DM*4);
  float* Pws    = (float*)alloc((size_t)BB*NC*DI*DS*4);
  float* Hws    = (float*)alloc((size_t)BB*NC*DI*DS*4);

  prep_weights<<<(WI_N+WX_N+WD_N+WO_N + 255)/256, 256, 0, stream>>>(
      w_inp, w_xprj, w_dtp, w_outp, wb_in, wb_xp, wb_dt, wb_out);

  const float* xprev = x_in;
  for (int l = 0; l < NL; ++l) {
    rmsnorm_kernel<<<MROWS, 256, 0, stream>>>(xprev, w_norm + l*DM, xn);

    // xz = xn @ in_proj^T : [2048, 3072], K=768; split x->fp32, z->bf16
    gemm_in128<<<dim3(MROWS/128, (2*DI)/128), 256, 0, stream>>>(
        xn, wb_in + (size_t)l*2*DI*DM, xzf, zb);

    conv_silu_kernel<<<(MROWS*DI)/256, 256, 0, stream>>>(
        xzf, w_conv + l*DI*DCONV, b_conv + l*DI, xcb);

    // dbc partials: [2048, 80], K=1536 split 4x384
    gemm64l<0><<<dim3(MROWS/64, XPN/64, KSPL), 256, 0, stream>>>(
        xcb, DI, wb_xp + (size_t)l*XPN*DI, DI, xpart, DBCW, DBCW, DI/KSPL, nullptr);

    xproj_reduce<<<(MROWS*DBCW)/256, 256, 0, stream>>>(xpart, dbcb, bcf);

    // delta = softplus(dbcb @ dt_w^T + dt_b) -> bf16 [2048, 1536], K=48
    gemm_dt<<<dim3(MROWS/64, DI/64), 256, 0, stream>>>(
        dbcb, wb_dt + (size_t)l*DI*DD, dltb, b_dt + l*DI);

    // chunked parallel scan
    scan_pass1<<<BB*NC*(DI/128), 256, 0, stream>>>(
        dltb, xcb, bcf, a_log + (size_t)l*DI*DS, Pws, Hws);
    scan_fix<<<(BB*DI*DS)/256, 256, 0, stream>>>(Pws, Hws);
    scan_pass2<<<BB*NC*(DI/128), 256, 0, stream>>>(
        dltb, xcb, bcf, a_log + (size_t)l*DI*DS, Hws, d_par + l*DI, zb, scb);

    // x_next = x_prev + scan_out @ out_proj^T : [2048, 768], K=1536
    float* xout = (l == NL-1) ? xfinal : x1;
    gemm64l<3><<<dim3(MROWS/64, DM/64, 1), 256, 0, stream>>>(
        scb, DI, wb_out + (size_t)l*DM*DI, DI, xout, DM, DM, DI, xprev);

    xprev = x1;
  }
}